// Round 3
// baseline (2811.793 us; speedup 1.0000x reference)
//
#include <hip/hip_runtime.h>
#include <math.h>

#define NN 50000
#define HH 384
#define KKC 16
#define PER 6250
#define EE 1600000
#define NKE 800000   // N*K

// ---------------- ws layout (bytes) ----------------
#define OFF_NBRS   0UL
#define OFF_WTS    12800000UL
#define OFF_ADJ    0UL
#define OFF_CNT2   25600000UL
#define OFF_ADJC   25800000UL
#define OFF_CLUS   26000000UL
#define OFF_MATE   26200000UL
#define OFF_NEWID  26400000UL
#define OFF_CMAP   26600000UL
#define OFF_REPOF  26800000UL
#define OFF_NC     27000000UL
#define OFF_AGGR   27000256UL

// K0: zero counters
__global__ void k0_init(int* cnt2, int* adjcnt) {
    int i = blockIdx.x * blockDim.x + threadIdx.x;
    if (i < NN) { cnt2[i] = 0; adjcnt[i] = 0; }
}

// K1: block-1 neighbors (the 16 out-edges, in storage order) + init rest
__global__ void k1_build(const int* __restrict__ ei, const float* __restrict__ ew,
                         int* __restrict__ nbrs, float* __restrict__ wts) {
    int id = blockIdx.x * blockDim.x + threadIdx.x;  // N*64
    if (id >= NN * 64) return;
    int slot = id & 63;
    int u = id >> 6;
    if (slot < KKC) {
        int e = u * KKC + slot;
        nbrs[id] = ei[EE + e];   // row1[e] = dst_orig
        wts[id]  = ew[e];
    } else {
        nbrs[id] = -1;
        wts[id]  = -INFINITY;
    }
}

// K2: scatter block-2 in-edges (store edge index i temporarily), unordered
__global__ void k2_scatter(const int* __restrict__ ei, int* __restrict__ cnt2,
                           int* __restrict__ nbrs) {
    int i = blockIdx.x * blockDim.x + threadIdx.x;   // NK
    if (i >= NKE) return;
    int u = ei[EE + i];
    int slot = atomicAdd(&cnt2[u], 1);
    if (slot < 48) nbrs[u * 64 + 16 + slot] = i;
}

// K3: per-node stable rank by edge index -> final neighbor/weight slots
__global__ __launch_bounds__(256) void k3_rank(const int* __restrict__ cnt2,
                                               const float* __restrict__ ew,
                                               int* __restrict__ nbrs,
                                               float* __restrict__ wts) {
    int gid = blockIdx.x * blockDim.x + threadIdx.x;
    int u = gid >> 6;
    int lane = gid & 63;
    if (u >= NN) return;
    int cnt = cnt2[u]; if (cnt > 48) cnt = 48;
    int myi = (lane < cnt) ? nbrs[u * 64 + 16 + lane] : 0x7FFFFFFF;
    int rank = 0;
    for (int m = 0; m < cnt; ++m) {
        int ov = __shfl(myi, m, 64);
        if (lane < cnt && m != lane && ov < myi) rank++;
    }
    if (lane < cnt) {
        nbrs[u * 64 + 16 + rank] = myi >> 4;        // /16 = src_orig = neighbor
        wts [u * 64 + 16 + rank] = ew[NKE + myi];
    }
}

// ---------------- K4: speculative sequential greedy matching ----------------
// Group of 4 steps: the matched-bitmap snapshot is complete through the group
// start (gathers issued after the previous group's LDS atomics; DS pipe is
// in-order per wave). Phase A runs 4 INDEPENDENT speculative argmax chains
// (DPP max-reduce) against that snapshot - pure ILP. Phase B serially commits:
// removing a non-max candidate never changes an argmax, so the speculative
// winner is exact unless it equals one of the <=3 in-group prior grabs
// (wA/wB/wC) - then one exact re-reduce (rare).
#define DPPMAX(x, ctrl) fmaxf((x), __int_as_float(__builtin_amdgcn_update_dpp( \
        (int)0xFF800000, __float_as_int(x), (ctrl), 0xf, 0xf, false)))

__device__ __forceinline__ float dpp_wavemax(float wv) {
    float m = wv;
    m = DPPMAX(m, 0x111);   // row_shr:1
    m = DPPMAX(m, 0x112);   // row_shr:2
    m = DPPMAX(m, 0x114);   // row_shr:4
    m = DPPMAX(m, 0x118);   // row_shr:8
    m = DPPMAX(m, 0x142);   // row_bcast:15
    m = DPPMAX(m, 0x143);   // row_bcast:31  -> lane 63 holds wave max
    return __int_as_float(__builtin_amdgcn_readlane(__float_as_int(m), 63));
}

__global__ __launch_bounds__(64) void k4_graclus(const int* __restrict__ nbrs,
                                                 const float* __restrict__ wts,
                                                 int* __restrict__ cluster,
                                                 int* __restrict__ mate) {
    __shared__ unsigned mbits[PER / 32 + 1];
    __shared__ int clus[PER];
    __shared__ int mt[PER];
    const int base = blockIdx.x * PER;
    const int lane = threadIdx.x;
    for (int i = lane; i < PER / 32 + 1; i += 64) mbits[i] = 0u;
    for (int i = lane; i < PER; i += 64) { clus[i] = i; mt[i] = -1; }
    __syncthreads();

    const int*   nrow = nbrs + (size_t)base * 64;
    const float* wrow = wts  + (size_t)base * 64;
    auto ldrow = [&](int r, int& nl, float& wt) {
        int rr = r < PER ? r : PER - 1;
        nl = nrow[(size_t)rr * 64 + lane] - base;   // invalid (-1) -> negative local
        wt = wrow[(size_t)rr * 64 + lane];
    };

    // 12-deep global row prefetch
    int   n0,n1,n2,n3, pb0,pb1,pb2,pb3, pc0,pc1,pc2,pc3;
    float w0,w1,w2,w3, qb0,qb1,qb2,qb3, qc0,qc1,qc2,qc3;
    ldrow(0,n0,w0);   ldrow(1,n1,w1);   ldrow(2,n2,w2);   ldrow(3,n3,w3);
    ldrow(4,pb0,qb0); ldrow(5,pb1,qb1); ldrow(6,pb2,qb2); ldrow(7,pb3,qb3);
    ldrow(8,pc0,qc0); ldrow(9,pc1,qc1); ldrow(10,pc2,qc2); ldrow(11,pc3,qc3);

    unsigned g0 = 0u, g1 = 0u, g2 = 0u, g3 = 0u;   // per-lane word of matched[nl]
    unsigned h0 = 0u, h1 = 0u, h2 = 0u, h3 = 0u;   // broadcast word of matched[u]
    int wA = -1, wB = -1, wC = -1;                 // last 3 grabs (exclusion window)

    // Phase A: speculative argmax against the group-start snapshot
    auto specArg = [&](int u, int nl, float wt, unsigned gw,
                       bool& candS, unsigned long long& em) -> int {
        candS = (nl > u) && !((gw >> (nl & 31)) & 1u);
        float wv = candS ? wt : -INFINITY;
        float wmax = dpp_wavemax(wv);
        em = __ballot(candS && (wv == wmax));
        return em ? __builtin_amdgcn_readlane(nl, (int)__builtin_ctzll(em)) : -1;
    };
    // Phase B: serial commit (scalar fast path, rare exact re-reduce)
    auto commit = [&](int u, int nl, float wt, unsigned hw, bool candS, int vl) {
        unsigned hword = (unsigned)__builtin_amdgcn_readfirstlane((int)hw);
        bool um = (((hword >> (u & 31)) & 1u) != 0u) ||
                  (u == wA) || (u == wB) || (u == wC);
        int vnew = -1;
        if (!um) {
            if (vl >= 0 && (vl == wA || vl == wB || vl == wC)) {
                // slow path: winner got grabbed in-group -> exact re-reduce
                bool cand = candS && (nl != wA) && (nl != wB) && (nl != wC);
                float wv = cand ? wt : -INFINITY;
                float wmax = dpp_wavemax(wv);
                unsigned long long em2 = __ballot(cand && (wv == wmax));
                vl = em2 ? __builtin_amdgcn_readlane(nl, (int)__builtin_ctzll(em2)) : -1;
            }
            if (vl >= 0) {
                if (lane == 0) {
                    atomicOr(&mbits[u  >> 5], 1u << (u  & 31));
                    atomicOr(&mbits[vl >> 5], 1u << (vl & 31));
                    mt[u] = vl; mt[vl] = u; clus[vl] = u;
                }
                vnew = vl;
            } else {
                if (lane == 0) atomicOr(&mbits[u >> 5], 1u << (u & 31));
            }
        }
        wC = wB; wB = wA; wA = vnew;
    };

    for (int u0 = 0; u0 < PER; u0 += 4) {
        bool c0, c1, c2, c3;
        unsigned long long e0, e1, e2, e3;
        int vl0 = specArg(u0 + 0, n0, w0, g0, c0, e0);
        int vl1 = specArg(u0 + 1, n1, w1, g1, c1, e1);
        int vl2 = specArg(u0 + 2, n2, w2, g2, c2, e2);
        int vl3 = specArg(u0 + 3, n3, w3, g3, c3, e3);
        commit(u0 + 0, n0, w0, h0, c0, vl0);
        if (u0 + 1 < PER) commit(u0 + 1, n1, w1, h1, c1, vl1);
        if (u0 + 2 < PER) commit(u0 + 2, n2, w2, h2, c2, vl2);
        if (u0 + 3 < PER) commit(u0 + 3, n3, w3, h3, c3, vl3);
        // pin order: this group's ds_or updates issue before next gathers
        __builtin_amdgcn_sched_barrier(0);
        g0 = mbits[(pb0 < 0 ? 0 : pb0) >> 5];  h0 = mbits[(u0 + 4) >> 5];
        g1 = mbits[(pb1 < 0 ? 0 : pb1) >> 5];  h1 = mbits[(u0 + 5) >> 5];
        g2 = mbits[(pb2 < 0 ? 0 : pb2) >> 5];  h2 = mbits[(u0 + 6) >> 5];
        g3 = mbits[(pb3 < 0 ? 0 : pb3) >> 5];  h3 = mbits[(u0 + 7) >> 5];
        // rotate row banks, prefetch rows u0+12..u0+15
        n0=pb0; w0=qb0; n1=pb1; w1=qb1; n2=pb2; w2=qb2; n3=pb3; w3=qb3;
        pb0=pc0; qb0=qc0; pb1=pc1; qb1=qc1; pb2=pc2; qb2=qc2; pb3=pc3; qb3=qc3;
        ldrow(u0+12, pc0, qc0); ldrow(u0+13, pc1, qc1);
        ldrow(u0+14, pc2, qc2); ldrow(u0+15, pc3, qc3);
    }
    __syncthreads();
    for (int i = lane; i < PER; i += 64) {
        cluster[base + i] = base + clus[i];
        int m = mt[i];
        mate[base + i] = (m < 0) ? -1 : base + m;
    }
}

// K5: single-block inclusive scan of is_rep -> new_id, nc
__global__ __launch_bounds__(1024) void k5_scan(const int* __restrict__ cluster,
                                                int* __restrict__ newid,
                                                int* __restrict__ ncp) {
    __shared__ int wsum[16];
    __shared__ int carry;
    const int tid = threadIdx.x;
    const int lane = tid & 63;
    const int wid = tid >> 6;
    if (tid == 0) carry = 0;
    __syncthreads();
    for (int bse = 0; bse < NN; bse += 1024) {
        int u = bse + tid;
        int v = (u < NN && cluster[u] == u) ? 1 : 0;
        int s = v;
        #pragma unroll
        for (int off = 1; off < 64; off <<= 1) {
            int t = __shfl_up(s, off, 64);
            if (lane >= off) s += t;
        }
        if (lane == 63) wsum[wid] = s;
        __syncthreads();
        if (wid == 0) {
            int w2 = (lane < 16) ? wsum[lane] : 0;
            #pragma unroll
            for (int off = 1; off < 16; off <<= 1) {
                int t = __shfl_up(w2, off, 64);
                if (lane >= off) w2 += t;
            }
            if (lane < 16) wsum[lane] = w2;
        }
        __syncthreads();
        int wpre = (wid > 0) ? wsum[wid - 1] : 0;
        int carryv = carry;
        if (u < NN) newid[u] = carryv + wpre + s - 1;
        int total = wsum[15];
        __syncthreads();
        if (tid == 0) carry = carryv + total;
        __syncthreads();
    }
    if (tid == 0) *ncp = carry;
}

// K6: cluster id map + representative lookup
__global__ void k6_relabel(const int* __restrict__ cluster, const int* __restrict__ newid,
                           int* __restrict__ cmap, int* __restrict__ repof) {
    int u = blockIdx.x * blockDim.x + threadIdx.x;
    if (u >= NN) return;
    int cl = cluster[u];
    int cid = newid[cl];
    cmap[u] = cid;
    if (cl == u) repof[cid] = u;
}

// K7: max-pool features into d_out's [N,H] region + pooled batch vector
__global__ __launch_bounds__(128) void k7_pool(const float* __restrict__ h,
                                               const int* __restrict__ repof,
                                               const int* __restrict__ mate,
                                               const int* __restrict__ batch,
                                               const int* __restrict__ ncp,
                                               float* __restrict__ xout,
                                               float* __restrict__ bpool) {
    int cid = blockIdx.x;
    int tid = threadIdx.x;
    int nc = *ncp;
    if (cid >= nc) {
        #pragma unroll
        for (int q = 0; q < 3; ++q) xout[(size_t)cid * HH + tid + q * 128] = 0.f;
        if (tid == 0) bpool[cid] = 0.f;
        return;
    }
    int u = repof[cid];
    int v = mate[u];
    const float* hu = h + (size_t)u * HH;
    const float* hv = h + (size_t)(v >= 0 ? v : u) * HH;
    #pragma unroll
    for (int q = 0; q < 3; ++q) {
        int j = tid + q * 128;
        float a = hu[j];
        if (v >= 0) a = fmaxf(a, hv[j]);
        xout[(size_t)cid * HH + j] = a;
    }
    if (tid == 0) bpool[cid] = (float)batch[u];
}

// K8: per-destination-cluster candidate source lists (with duplicates)
__global__ void k8_adj(const int* __restrict__ ei, const int* __restrict__ cmap,
                       int* __restrict__ adjcnt, int* __restrict__ adj) {
    int g = blockIdx.x * blockDim.x + threadIdx.x;
    if (g >= EE) return;
    int cs = cmap[ei[g]];
    int cd = cmap[ei[EE + g]];
    if (cs == cd) return;
    int slot = atomicAdd(&adjcnt[cd], 1);
    if (slot < 128) adj[(size_t)cd * 128 + slot] = cs;
}

// K9: dedupe + sum pooled rows -> aggr
__global__ __launch_bounds__(128) void k9_aggr(const int* __restrict__ adjcnt,
                                               const int* __restrict__ adj,
                                               const float* __restrict__ x,
                                               const int* __restrict__ ncp,
                                               float* __restrict__ aggr) {
    int cid = blockIdx.x;
    int tid = threadIdx.x;
    if (cid >= *ncp) return;
    int cnt = adjcnt[cid]; if (cnt > 128) cnt = 128;
    __shared__ int vals[128];
    __shared__ int keep[128];
    if (tid < cnt) vals[tid] = adj[(size_t)cid * 128 + tid];
    __syncthreads();
    if (tid < cnt) {
        int v = vals[tid]; int k = 1;
        for (int m = 0; m < tid; ++m) if (vals[m] == v) { k = 0; break; }
        keep[tid] = k;
    }
    __syncthreads();
    float a0 = 0.f, a1 = 0.f, a2 = 0.f;
    for (int e = 0; e < cnt; ++e) {
        if (keep[e]) {
            const float* xr = x + (size_t)vals[e] * HH;
            a0 += xr[tid]; a1 += xr[tid + 128]; a2 += xr[tid + 256];
        }
    }
    aggr[(size_t)cid * HH + tid]       = a0;
    aggr[(size_t)cid * HH + tid + 128] = a1;
    aggr[(size_t)cid * HH + tid + 256] = a2;
}

// K10: out = relu([aggr | max(h_u,h_v)] @ [Wrel|Wroot]^T + b_rel)
// 128x128 tile, 8x8 accum per thread (FMA:LDS-read = 16:1)
__global__ __launch_bounds__(256) void k10_gemm(const float* __restrict__ aggr,
                                                const float* __restrict__ h,
                                                const int* __restrict__ repof,
                                                const int* __restrict__ mate,
                                                const float* __restrict__ Wrel,
                                                const float* __restrict__ Wroot,
                                                const float* __restrict__ brel,
                                                float* __restrict__ out,
                                                const int* __restrict__ ncp) {
    const int nc = *ncp;
    const int row0 = blockIdx.x * 128;
    const int col0 = blockIdx.y * 128;
    if (row0 >= nc) return;
    __shared__ float As[16][132];
    __shared__ float Ws[16][132];
    __shared__ int us[128], vs[128];
    const int tid = threadIdx.x;
    if (tid < 128) {
        int r = row0 + tid;
        int u = 0, v = -1;
        if (r < nc) { u = repof[r]; v = mate[u]; }
        us[tid] = u; vs[tid] = v;
    }
    __syncthreads();
    float acc[8][8] = {};
    const int ty = tid >> 4, tx = tid & 15;
    for (int kt = 0; kt < 2 * HH; kt += 16) {
        #pragma unroll
        for (int q = 0; q < 2; ++q) {
            int flat = tid + q * 256;           // 0..511
            int r    = flat >> 2;               // 0..127
            int kq   = (flat & 3) << 2;         // 0,4,8,12
            int k    = kt + kq;
            int grow = row0 + r;
            bool rv  = (grow < nc);
            float4 val;
            if (k < HH) {
                val = *(const float4*)(aggr + (size_t)(rv ? grow : 0) * HH + k);
            } else {
                int kk = k - HH;
                int u = us[r], v = vs[r];
                float4 a = *(const float4*)(h + (size_t)u * HH + kk);
                if (v >= 0) {
                    float4 b = *(const float4*)(h + (size_t)v * HH + kk);
                    a.x = fmaxf(a.x, b.x); a.y = fmaxf(a.y, b.y);
                    a.z = fmaxf(a.z, b.z); a.w = fmaxf(a.w, b.w);
                }
                val = a;
            }
            if (!rv) val = make_float4(0.f, 0.f, 0.f, 0.f);
            As[kq + 0][r] = val.x; As[kq + 1][r] = val.y;
            As[kq + 2][r] = val.z; As[kq + 3][r] = val.w;
        }
        {
            const float* Wsrc = (kt < HH) ? Wrel : Wroot;
            int kk0 = (kt < HH) ? kt : kt - HH;
            #pragma unroll
            for (int q = 0; q < 2; ++q) {
                int flat = tid + q * 256;
                int j    = flat >> 2;
                int kq   = (flat & 3) << 2;
                float4 w = *(const float4*)(Wsrc + (size_t)(col0 + j) * HH + kk0 + kq);
                Ws[kq + 0][j] = w.x; Ws[kq + 1][j] = w.y;
                Ws[kq + 2][j] = w.z; Ws[kq + 3][j] = w.w;
            }
        }
        __syncthreads();
        #pragma unroll
        for (int k = 0; k < 16; ++k) {
            float a[8], w[8];
            #pragma unroll
            for (int i = 0; i < 8; ++i) a[i] = As[k][ty * 8 + i];
            #pragma unroll
            for (int n = 0; n < 8; ++n) w[n] = Ws[k][tx * 8 + n];
            #pragma unroll
            for (int i = 0; i < 8; ++i)
                #pragma unroll
                for (int n = 0; n < 8; ++n)
                    acc[i][n] += a[i] * w[n];
        }
        __syncthreads();
    }
    #pragma unroll
    for (int i = 0; i < 8; ++i) {
        int r = row0 + ty * 8 + i;
        if (r >= nc) continue;
        #pragma unroll
        for (int n = 0; n < 8; ++n) {
            int j = col0 + tx * 8 + n;
            float v = acc[i][n] + brel[j];
            out[(size_t)r * HH + j] = v > 0.f ? v : 0.f;
        }
    }
}

extern "C" void kernel_launch(void* const* d_in, const int* in_sizes, int n_in,
                              void* d_out, int out_size, void* d_ws, size_t ws_size,
                              hipStream_t stream) {
    const float* h     = (const float*)d_in[0];
    const int*   ei    = (const int*)d_in[1];
    const float* ew    = (const float*)d_in[2];
    const int*   batch = (const int*)d_in[3];
    const float* Wrel  = (const float*)d_in[4];
    const float* brel  = (const float*)d_in[5];
    const float* Wroot = (const float*)d_in[6];
    float* out = (float*)d_out;

    unsigned char* w8 = (unsigned char*)d_ws;
    int*   nbrs   = (int*)(w8 + OFF_NBRS);
    float* wts    = (float*)(w8 + OFF_WTS);
    int*   adj    = (int*)(w8 + OFF_ADJ);
    int*   cnt2   = (int*)(w8 + OFF_CNT2);
    int*   adjcnt = (int*)(w8 + OFF_ADJC);
    int*   clus   = (int*)(w8 + OFF_CLUS);
    int*   mate   = (int*)(w8 + OFF_MATE);
    int*   newid  = (int*)(w8 + OFF_NEWID);
    int*   cmap   = (int*)(w8 + OFF_CMAP);
    int*   repof  = (int*)(w8 + OFF_REPOF);
    int*   ncp    = (int*)(w8 + OFF_NC);
    float* aggr   = (float*)(w8 + OFF_AGGR);

    float* xout  = out;
    float* bpool = out + (size_t)NN * HH;

    hipLaunchKernelGGL(k0_init,    dim3((NN + 255) / 256), dim3(256), 0, stream, cnt2, adjcnt);
    hipLaunchKernelGGL(k1_build,   dim3((NN * 64 + 255) / 256), dim3(256), 0, stream, ei, ew, nbrs, wts);
    hipLaunchKernelGGL(k2_scatter, dim3((NKE + 255) / 256), dim3(256), 0, stream, ei, cnt2, nbrs);
    hipLaunchKernelGGL(k3_rank,    dim3((NN * 64 + 255) / 256), dim3(256), 0, stream, cnt2, ew, nbrs, wts);
    hipLaunchKernelGGL(k4_graclus, dim3(8), dim3(64), 0, stream, nbrs, wts, clus, mate);
    hipLaunchKernelGGL(k5_scan,    dim3(1), dim3(1024), 0, stream, clus, newid, ncp);
    hipLaunchKernelGGL(k6_relabel, dim3((NN + 255) / 256), dim3(256), 0, stream, clus, newid, cmap, repof);
    hipLaunchKernelGGL(k7_pool,    dim3(NN), dim3(128), 0, stream, h, repof, mate, batch, ncp, xout, bpool);
    hipLaunchKernelGGL(k8_adj,     dim3((EE + 255) / 256), dim3(256), 0, stream, ei, cmap, adjcnt, adj);
    hipLaunchKernelGGL(k9_aggr,    dim3(NN), dim3(128), 0, stream, adjcnt, adj, xout, ncp, aggr);
    hipLaunchKernelGGL(k10_gemm,   dim3((NN + 127) / 128, HH / 128), dim3(256), 0, stream,
                       aggr, h, repof, mate, Wrel, Wroot, brel, out, ncp);
}

// Round 6
// 2399.239 us; speedup vs baseline: 1.1720x; 1.1720x over previous
//
#include <hip/hip_runtime.h>
#include <math.h>

#define NN 50000
#define HH 384
#define KKC 16
#define PER 6250
#define EE 1600000
#define NKE 800000   // N*K
#define CP 256       // graclus chunk size

// ---------------- ws layout (bytes) ----------------
#define OFF_NBRS   0UL
#define OFF_WTS    12800000UL
#define OFF_ADJ    0UL
#define OFF_CNT2   25600000UL
#define OFF_ADJC   25800000UL
#define OFF_CLUS   26000000UL
#define OFF_MATE   26200000UL
#define OFF_NEWID  26400000UL
#define OFF_CMAP   26600000UL
#define OFF_REPOF  26800000UL
#define OFF_NC     27000000UL
#define OFF_AGGR   27000256UL

// K0: zero counters + init cluster/mate (k4 writes only matched pairs)
__global__ void k0_init(int* cnt2, int* adjcnt, int* cluster, int* mate) {
    int i = blockIdx.x * blockDim.x + threadIdx.x;
    if (i < NN) { cnt2[i] = 0; adjcnt[i] = 0; cluster[i] = i; mate[i] = -1; }
}

// K1: block-1 neighbors (the 16 out-edges, in storage order) + init rest
__global__ void k1_build(const int* __restrict__ ei, const float* __restrict__ ew,
                         int* __restrict__ nbrs, float* __restrict__ wts) {
    int id = blockIdx.x * blockDim.x + threadIdx.x;  // N*64
    if (id >= NN * 64) return;
    int slot = id & 63;
    int u = id >> 6;
    if (slot < KKC) {
        int e = u * KKC + slot;
        nbrs[id] = ei[EE + e];   // row1[e] = dst_orig
        wts[id]  = ew[e];
    } else {
        nbrs[id] = -1;
        wts[id]  = -INFINITY;
    }
}

// K2: scatter block-2 in-edges (store edge index i temporarily), unordered
__global__ void k2_scatter(const int* __restrict__ ei, int* __restrict__ cnt2,
                           int* __restrict__ nbrs) {
    int i = blockIdx.x * blockDim.x + threadIdx.x;   // NK
    if (i >= NKE) return;
    int u = ei[EE + i];
    int slot = atomicAdd(&cnt2[u], 1);
    if (slot < 48) nbrs[u * 64 + 16 + slot] = i;
}

// K3: per-node stable rank by edge index -> final neighbor/weight slots
__global__ __launch_bounds__(256) void k3_rank(const int* __restrict__ cnt2,
                                               const float* __restrict__ ew,
                                               int* __restrict__ nbrs,
                                               float* __restrict__ wts) {
    int gid = blockIdx.x * blockDim.x + threadIdx.x;
    int u = gid >> 6;
    int lane = gid & 63;
    if (u >= NN) return;
    int cnt = cnt2[u]; if (cnt > 48) cnt = 48;
    int myi = (lane < cnt) ? nbrs[u * 64 + 16 + lane] : 0x7FFFFFFF;
    int rank = 0;
    for (int m = 0; m < cnt; ++m) {
        int ov = __shfl(myi, m, 64);
        if (lane < cnt && m != lane && ov < myi) rank++;
    }
    if (lane < cnt) {
        nbrs[u * 64 + 16 + rank] = myi >> 4;        // /16 = src_orig = neighbor
        wts [u * 64 + 16 + rank] = ew[NKE + myi];
    }
}

// ---------------- K4: chunked speculative matching, INLINE conflict fix ----
// Spec (8 waves, parallel): per-node argmax over "unmatched at chunk start".
// Exact unless the winner was grabbed earlier IN THIS PASS (candidates are
// all > u, so the only removals at u's turn are this pass's winners; removing
// non-max candidates never changes an argmax or its first-slot tie-break).
// Walk (wave 0, ascending order): winners kept in 4 lane-buffers (uniform
// v_cmp+ballot membership). On conflict: reload u's row, gather FRESH mbits
// (same-wave DS pipe is in-order, prior ds_or visible), one exact re-reduce,
// commit immediately -- actor order preserved exactly.
#define DPPMAX(x, ctrl) fmaxf((x), __int_as_float(__builtin_amdgcn_update_dpp( \
        (int)0xFF800000, __float_as_int(x), (ctrl), 0xf, 0xf, false)))

__device__ __forceinline__ float dpp_wavemax(float wv) {
    float m = wv;
    m = DPPMAX(m, 0x111);   // row_shr:1
    m = DPPMAX(m, 0x112);   // row_shr:2
    m = DPPMAX(m, 0x114);   // row_shr:4
    m = DPPMAX(m, 0x118);   // row_shr:8
    m = DPPMAX(m, 0x142);   // row_bcast:15
    m = DPPMAX(m, 0x143);   // row_bcast:31  -> lane 63 holds wave max
    return __int_as_float(__builtin_amdgcn_readlane(__float_as_int(m), 63));
}

// argmax over snapshot-unmatched later neighbors; -1 = no candidate
__device__ __forceinline__ int spec_reduce(int u, int nl, float wt, unsigned gw) {
    bool cand = (nl > u) && !((gw >> (nl & 31)) & 1u);
    float wv = cand ? wt : -INFINITY;
    float wmax = dpp_wavemax(wv);
    unsigned long long em = __ballot(cand && (wv == wmax));
    return em ? __builtin_amdgcn_readlane(nl, (int)__builtin_ctzll(em)) : -1;
}

// winners-set membership / append (values are BLOCK-local node ids >= 0)
#define MEMB(x) (((__ballot(b0==(x)) | __ballot(b1==(x))) | \
                  (__ballot(b2==(x)) | __ballot(b3==(x)))) != 0ULL)
#define APPW(x) { int _x=(x); \
                  if (wcnt<64)       { if (lane==wcnt)     b0=_x; } \
                  else if (wcnt<128) { if (lane==wcnt-64)  b1=_x; } \
                  else if (wcnt<192) { if (lane==wcnt-128) b2=_x; } \
                  else               { if (lane==wcnt-192) b3=_x; } wcnt++; }

__global__ __launch_bounds__(512) void k4_graclus(const int* __restrict__ nbrs,
                                                  const float* __restrict__ wts,
                                                  int* __restrict__ cluster,
                                                  int* __restrict__ mate) {
    __shared__ unsigned mbits[PER / 32 + 1];
    __shared__ int win_lds[CP];
    const int base = blockIdx.x * PER;
    const int tid  = threadIdx.x;
    const int lane = tid & 63;
    const int wvid = tid >> 6;
    for (int i = tid; i < PER / 32 + 1; i += 512) mbits[i] = 0u;
    __syncthreads();
    const int*   nrow = nbrs + (size_t)base * 64;
    const float* wrow = wts  + (size_t)base * 64;

    for (int t = 0; t < PER; t += CP) {
        const int wl = (PER - t < CP) ? (PER - t) : CP;
        // ---------- spec: 8 waves x 32 nodes, vs chunk-start snapshot ----
        {
            const int j0 = t + wvid * 32;
            if (j0 < PER) {
                int RN[8]; float RW[8];
                #pragma unroll
                for (int p = 0; p < 8; ++p) {
                    int rr = j0 + p; rr = rr < PER ? rr : PER - 1;
                    RN[p] = nrow[(size_t)rr * 64 + lane] - base;
                    RW[p] = wrow[(size_t)rr * 64 + lane];
                }
                unsigned gcur = mbits[(RN[0] < 0 ? 0 : RN[0]) >> 5];
                unsigned hcur = mbits[j0 >> 5];
                #pragma unroll
                for (int j = 0; j < 32; ++j) {
                    const int u = j0 + j;
                    unsigned gnx = 0u, hnx = 0u;
                    if (j + 1 < 32) {
                        int nn = RN[(j + 1) & 7];
                        gnx = mbits[(nn < 0 ? 0 : nn) >> 5];
                        hnx = mbits[(u + 1) >> 5];
                    }
                    if (u < PER) {
                        int w;
                        unsigned hword = (unsigned)__builtin_amdgcn_readfirstlane((int)hcur);
                        if ((hword >> (u & 31)) & 1u) w = -2;                // matched pre-chunk
                        else w = spec_reduce(u, RN[j & 7], RW[j & 7], gcur); // -1 or winner
                        if (lane == 0) win_lds[u - t] = w;
                    }
                    if (j + 8 < 32) {
                        int rr = j0 + j + 8; rr = rr < PER ? rr : PER - 1;
                        RN[j & 7] = nrow[(size_t)rr * 64 + lane] - base;
                        RW[j & 7] = wrow[(size_t)rr * 64 + lane];
                    }
                    gcur = gnx; hcur = hnx;
                }
            }
        }
        __syncthreads();
        // ---------- commit walk (wave 0, serial in ascending order) ----
        if (wvid == 0) {
            int b0 = -3, b1 = -3, b2 = -3, b3 = -3;
            int wcnt = 0;
            auto commit = [&](int ug, int w) {       // both BLOCK-local
                APPW(w);
                if (lane == 0) {
                    atomicOr(&mbits[w >> 5], 1u << (w & 31));
                    mate[base + ug] = base + w;
                    mate[base + w]  = base + ug;
                    cluster[base + w] = base + ug;
                }
            };
            auto doStep = [&](int j, int w) {        // j chunk-local actor
                if (w < 0) return;                   // -2 pre-matched / -1 single (final)
                int ug = t + j;
                if (MEMB(ug)) return;                // grabbed earlier this pass
                if (!MEMB(w)) { commit(ug, w); return; }
                // conflict (rare): exact inline re-resolve vs fresh state
                int nl   = nrow[(size_t)ug * 64 + lane] - base;
                float w2t = wrow[(size_t)ug * 64 + lane];
                unsigned gw = mbits[(nl < 0 ? 0 : nl) >> 5]; // sees prior ds_or (in-order DS)
                int w2 = spec_reduce(ug, nl, w2t, gw);
                if (w2 >= 0) commit(ug, w2);
            };
            int va = win_lds[lane];
            int vb = win_lds[64 + lane];
            int vc = win_lds[128 + lane];
            int vd = win_lds[192 + lane];
            for (int j = 0; j < 64 && j < wl; ++j)
                doStep(j,       __builtin_amdgcn_readlane(va, j));
            for (int j = 0; j < 64 && 64 + j < wl; ++j)
                doStep(64 + j,  __builtin_amdgcn_readlane(vb, j));
            for (int j = 0; j < 64 && 128 + j < wl; ++j)
                doStep(128 + j, __builtin_amdgcn_readlane(vc, j));
            for (int j = 0; j < 64 && 192 + j < wl; ++j)
                doStep(192 + j, __builtin_amdgcn_readlane(vd, j));
        }
        __syncthreads();
    }
}

// K5: single-block inclusive scan of is_rep -> new_id, nc
__global__ __launch_bounds__(1024) void k5_scan(const int* __restrict__ cluster,
                                                int* __restrict__ newid,
                                                int* __restrict__ ncp) {
    __shared__ int wsum[16];
    __shared__ int carry;
    const int tid = threadIdx.x;
    const int lane = tid & 63;
    const int wid = tid >> 6;
    if (tid == 0) carry = 0;
    __syncthreads();
    for (int bse = 0; bse < NN; bse += 1024) {
        int u = bse + tid;
        int v = (u < NN && cluster[u] == u) ? 1 : 0;
        int s = v;
        #pragma unroll
        for (int off = 1; off < 64; off <<= 1) {
            int t = __shfl_up(s, off, 64);
            if (lane >= off) s += t;
        }
        if (lane == 63) wsum[wid] = s;
        __syncthreads();
        if (wid == 0) {
            int w2 = (lane < 16) ? wsum[lane] : 0;
            #pragma unroll
            for (int off = 1; off < 16; off <<= 1) {
                int t = __shfl_up(w2, off, 64);
                if (lane >= off) w2 += t;
            }
            if (lane < 16) wsum[lane] = w2;
        }
        __syncthreads();
        int wpre = (wid > 0) ? wsum[wid - 1] : 0;
        int carryv = carry;
        if (u < NN) newid[u] = carryv + wpre + s - 1;
        int total = wsum[15];
        __syncthreads();
        if (tid == 0) carry = carryv + total;
        __syncthreads();
    }
    if (tid == 0) *ncp = carry;
}

// K6: cluster id map + representative lookup
__global__ void k6_relabel(const int* __restrict__ cluster, const int* __restrict__ newid,
                           int* __restrict__ cmap, int* __restrict__ repof) {
    int u = blockIdx.x * blockDim.x + threadIdx.x;
    if (u >= NN) return;
    int cl = cluster[u];
    int cid = newid[cl];
    cmap[u] = cid;
    if (cl == u) repof[cid] = u;
}

// K7: max-pool features into d_out's [N,H] region + pooled batch vector
__global__ __launch_bounds__(128) void k7_pool(const float* __restrict__ h,
                                               const int* __restrict__ repof,
                                               const int* __restrict__ mate,
                                               const int* __restrict__ batch,
                                               const int* __restrict__ ncp,
                                               float* __restrict__ xout,
                                               float* __restrict__ bpool) {
    int cid = blockIdx.x;
    int tid = threadIdx.x;
    int nc = *ncp;
    if (cid >= nc) {
        #pragma unroll
        for (int q = 0; q < 3; ++q) xout[(size_t)cid * HH + tid + q * 128] = 0.f;
        if (tid == 0) bpool[cid] = 0.f;
        return;
    }
    int u = repof[cid];
    int v = mate[u];
    const float* hu = h + (size_t)u * HH;
    const float* hv = h + (size_t)(v >= 0 ? v : u) * HH;
    #pragma unroll
    for (int q = 0; q < 3; ++q) {
        int j = tid + q * 128;
        float a = hu[j];
        if (v >= 0) a = fmaxf(a, hv[j]);
        xout[(size_t)cid * HH + j] = a;
    }
    if (tid == 0) bpool[cid] = (float)batch[u];
}

// K8: per-destination-cluster candidate source lists (with duplicates)
__global__ void k8_adj(const int* __restrict__ ei, const int* __restrict__ cmap,
                       int* __restrict__ adjcnt, int* __restrict__ adj) {
    int g = blockIdx.x * blockDim.x + threadIdx.x;
    if (g >= EE) return;
    int cs = cmap[ei[g]];
    int cd = cmap[ei[EE + g]];
    if (cs == cd) return;
    int slot = atomicAdd(&adjcnt[cd], 1);
    if (slot < 128) adj[(size_t)cd * 128 + slot] = cs;
}

// K9: dedupe + sum pooled rows -> aggr
__global__ __launch_bounds__(128) void k9_aggr(const int* __restrict__ adjcnt,
                                               const int* __restrict__ adj,
                                               const float* __restrict__ x,
                                               const int* __restrict__ ncp,
                                               float* __restrict__ aggr) {
    int cid = blockIdx.x;
    int tid = threadIdx.x;
    if (cid >= *ncp) return;
    int cnt = adjcnt[cid]; if (cnt > 128) cnt = 128;
    __shared__ int vals[128];
    __shared__ int keep[128];
    if (tid < cnt) vals[tid] = adj[(size_t)cid * 128 + tid];
    __syncthreads();
    if (tid < cnt) {
        int v = vals[tid]; int k = 1;
        for (int m = 0; m < tid; ++m) if (vals[m] == v) { k = 0; break; }
        keep[tid] = k;
    }
    __syncthreads();
    float a0 = 0.f, a1 = 0.f, a2 = 0.f;
    for (int e = 0; e < cnt; ++e) {
        if (keep[e]) {
            const float* xr = x + (size_t)vals[e] * HH;
            a0 += xr[tid]; a1 += xr[tid + 128]; a2 += xr[tid + 256];
        }
    }
    aggr[(size_t)cid * HH + tid]       = a0;
    aggr[(size_t)cid * HH + tid + 128] = a1;
    aggr[(size_t)cid * HH + tid + 256] = a2;
}

// K10: out = relu([aggr | max(h_u,h_v)] @ [Wrel|Wroot]^T + b_rel)
// 128x128 tile, 8x8 accum per thread
__global__ __launch_bounds__(256) void k10_gemm(const float* __restrict__ aggr,
                                                const float* __restrict__ h,
                                                const int* __restrict__ repof,
                                                const int* __restrict__ mate,
                                                const float* __restrict__ Wrel,
                                                const float* __restrict__ Wroot,
                                                const float* __restrict__ brel,
                                                float* __restrict__ out,
                                                const int* __restrict__ ncp) {
    const int nc = *ncp;
    const int row0 = blockIdx.x * 128;
    const int col0 = blockIdx.y * 128;
    if (row0 >= nc) return;
    __shared__ float As[16][132];
    __shared__ float Ws[16][132];
    __shared__ int us[128], vs[128];
    const int tid = threadIdx.x;
    if (tid < 128) {
        int r = row0 + tid;
        int u = 0, v = -1;
        if (r < nc) { u = repof[r]; v = mate[u]; }
        us[tid] = u; vs[tid] = v;
    }
    __syncthreads();
    float acc[8][8] = {};
    const int ty = tid >> 4, tx = tid & 15;
    for (int kt = 0; kt < 2 * HH; kt += 16) {
        #pragma unroll
        for (int q = 0; q < 2; ++q) {
            int flat = tid + q * 256;           // 0..511
            int r    = flat >> 2;               // 0..127
            int kq   = (flat & 3) << 2;         // 0,4,8,12
            int k    = kt + kq;
            int grow = row0 + r;
            bool rv  = (grow < nc);
            float4 val;
            if (k < HH) {
                val = *(const float4*)(aggr + (size_t)(rv ? grow : 0) * HH + k);
            } else {
                int kk = k - HH;
                int u = us[r], v = vs[r];
                float4 a = *(const float4*)(h + (size_t)u * HH + kk);
                if (v >= 0) {
                    float4 b = *(const float4*)(h + (size_t)v * HH + kk);
                    a.x = fmaxf(a.x, b.x); a.y = fmaxf(a.y, b.y);
                    a.z = fmaxf(a.z, b.z); a.w = fmaxf(a.w, b.w);
                }
                val = a;
            }
            if (!rv) val = make_float4(0.f, 0.f, 0.f, 0.f);
            As[kq + 0][r] = val.x; As[kq + 1][r] = val.y;
            As[kq + 2][r] = val.z; As[kq + 3][r] = val.w;
        }
        {
            const float* Wsrc = (kt < HH) ? Wrel : Wroot;
            int kk0 = (kt < HH) ? kt : kt - HH;
            #pragma unroll
            for (int q = 0; q < 2; ++q) {
                int flat = tid + q * 256;
                int j    = flat >> 2;
                int kq   = (flat & 3) << 2;
                float4 w = *(const float4*)(Wsrc + (size_t)(col0 + j) * HH + kk0 + kq);
                Ws[kq + 0][j] = w.x; Ws[kq + 1][j] = w.y;
                Ws[kq + 2][j] = w.z; Ws[kq + 3][j] = w.w;
            }
        }
        __syncthreads();
        #pragma unroll
        for (int k = 0; k < 16; ++k) {
            float a[8], w[8];
            #pragma unroll
            for (int i = 0; i < 8; ++i) a[i] = As[k][ty * 8 + i];
            #pragma unroll
            for (int n = 0; n < 8; ++n) w[n] = Ws[k][tx * 8 + n];
            #pragma unroll
            for (int i = 0; i < 8; ++i)
                #pragma unroll
                for (int n = 0; n < 8; ++n)
                    acc[i][n] += a[i] * w[n];
        }
        __syncthreads();
    }
    #pragma unroll
    for (int i = 0; i < 8; ++i) {
        int r = row0 + ty * 8 + i;
        if (r >= nc) continue;
        #pragma unroll
        for (int n = 0; n < 8; ++n) {
            int j = col0 + tx * 8 + n;
            float v = acc[i][n] + brel[j];
            out[(size_t)r * HH + j] = v > 0.f ? v : 0.f;
        }
    }
}

extern "C" void kernel_launch(void* const* d_in, const int* in_sizes, int n_in,
                              void* d_out, int out_size, void* d_ws, size_t ws_size,
                              hipStream_t stream) {
    const float* h     = (const float*)d_in[0];
    const int*   ei    = (const int*)d_in[1];
    const float* ew    = (const float*)d_in[2];
    const int*   batch = (const int*)d_in[3];
    const float* Wrel  = (const float*)d_in[4];
    const float* brel  = (const float*)d_in[5];
    const float* Wroot = (const float*)d_in[6];
    float* out = (float*)d_out;

    unsigned char* w8 = (unsigned char*)d_ws;
    int*   nbrs   = (int*)(w8 + OFF_NBRS);
    float* wts    = (float*)(w8 + OFF_WTS);
    int*   adj    = (int*)(w8 + OFF_ADJ);
    int*   cnt2   = (int*)(w8 + OFF_CNT2);
    int*   adjcnt = (int*)(w8 + OFF_ADJC);
    int*   clus   = (int*)(w8 + OFF_CLUS);
    int*   mate   = (int*)(w8 + OFF_MATE);
    int*   newid  = (int*)(w8 + OFF_NEWID);
    int*   cmap   = (int*)(w8 + OFF_CMAP);
    int*   repof  = (int*)(w8 + OFF_REPOF);
    int*   ncp    = (int*)(w8 + OFF_NC);
    float* aggr   = (float*)(w8 + OFF_AGGR);

    float* xout  = out;
    float* bpool = out + (size_t)NN * HH;

    hipLaunchKernelGGL(k0_init,    dim3((NN + 255) / 256), dim3(256), 0, stream, cnt2, adjcnt, clus, mate);
    hipLaunchKernelGGL(k1_build,   dim3((NN * 64 + 255) / 256), dim3(256), 0, stream, ei, ew, nbrs, wts);
    hipLaunchKernelGGL(k2_scatter, dim3((NKE + 255) / 256), dim3(256), 0, stream, ei, cnt2, nbrs);
    hipLaunchKernelGGL(k3_rank,    dim3((NN * 64 + 255) / 256), dim3(256), 0, stream, cnt2, ew, nbrs, wts);
    hipLaunchKernelGGL(k4_graclus, dim3(8), dim3(512), 0, stream, nbrs, wts, clus, mate);
    hipLaunchKernelGGL(k5_scan,    dim3(1), dim3(1024), 0, stream, clus, newid, ncp);
    hipLaunchKernelGGL(k6_relabel, dim3((NN + 255) / 256), dim3(256), 0, stream, clus, newid, cmap, repof);
    hipLaunchKernelGGL(k7_pool,    dim3(NN), dim3(128), 0, stream, h, repof, mate, batch, ncp, xout, bpool);
    hipLaunchKernelGGL(k8_adj,     dim3((EE + 255) / 256), dim3(256), 0, stream, ei, cmap, adjcnt, adj);
    hipLaunchKernelGGL(k9_aggr,    dim3(NN), dim3(128), 0, stream, adjcnt, adj, xout, ncp, aggr);
    hipLaunchKernelGGL(k10_gemm,   dim3((NN + 127) / 128, HH / 128), dim3(256), 0, stream,
                       aggr, h, repof, mate, Wrel, Wroot, brel, out, ncp);
}

// Round 7
// 2027.882 us; speedup vs baseline: 1.3866x; 1.1831x over previous
//
#include <hip/hip_runtime.h>
#include <math.h>

#define NN 50000
#define HH 384
#define KKC 16
#define PER 6250
#define EE 1600000
#define NKE 800000   // N*K
#define CP 256       // graclus chunk size

// ---------------- ws layout (bytes) ----------------
#define OFF_NBRS   0UL
#define OFF_WTS    12800000UL
#define OFF_ADJ    0UL
#define OFF_CNT2   25600000UL
#define OFF_ADJC   25800000UL
#define OFF_CLUS   26000000UL
#define OFF_MATE   26200000UL
#define OFF_NEWID  26400000UL
#define OFF_CMAP   26600000UL
#define OFF_REPOF  26800000UL
#define OFF_NC     27000000UL
#define OFF_AGGR   27000256UL

// K0: zero counters + init cluster/mate (k4 writes only matched pairs)
__global__ void k0_init(int* cnt2, int* adjcnt, int* cluster, int* mate) {
    int i = blockIdx.x * blockDim.x + threadIdx.x;
    if (i < NN) { cnt2[i] = 0; adjcnt[i] = 0; cluster[i] = i; mate[i] = -1; }
}

// K1: block-1 neighbors (the 16 out-edges, in storage order) + init rest
__global__ void k1_build(const int* __restrict__ ei, const float* __restrict__ ew,
                         int* __restrict__ nbrs, float* __restrict__ wts) {
    int id = blockIdx.x * blockDim.x + threadIdx.x;  // N*64
    if (id >= NN * 64) return;
    int slot = id & 63;
    int u = id >> 6;
    if (slot < KKC) {
        int e = u * KKC + slot;
        nbrs[id] = ei[EE + e];   // row1[e] = dst_orig
        wts[id]  = ew[e];
    } else {
        nbrs[id] = -1;
        wts[id]  = -INFINITY;
    }
}

// K2: scatter block-2 in-edges (store edge index i temporarily), unordered
__global__ void k2_scatter(const int* __restrict__ ei, int* __restrict__ cnt2,
                           int* __restrict__ nbrs) {
    int i = blockIdx.x * blockDim.x + threadIdx.x;   // NK
    if (i >= NKE) return;
    int u = ei[EE + i];
    int slot = atomicAdd(&cnt2[u], 1);
    if (slot < 48) nbrs[u * 64 + 16 + slot] = i;
}

// K3: per-node stable rank by edge index -> final neighbor/weight slots
__global__ __launch_bounds__(256) void k3_rank(const int* __restrict__ cnt2,
                                               const float* __restrict__ ew,
                                               int* __restrict__ nbrs,
                                               float* __restrict__ wts) {
    int gid = blockIdx.x * blockDim.x + threadIdx.x;
    int u = gid >> 6;
    int lane = gid & 63;
    if (u >= NN) return;
    int cnt = cnt2[u]; if (cnt > 48) cnt = 48;
    int myi = (lane < cnt) ? nbrs[u * 64 + 16 + lane] : 0x7FFFFFFF;
    int rank = 0;
    for (int m = 0; m < cnt; ++m) {
        int ov = __shfl(myi, m, 64);
        if (lane < cnt && m != lane && ov < myi) rank++;
    }
    if (lane < cnt) {
        nbrs[u * 64 + 16 + rank] = myi >> 4;        // /16 = src_orig = neighbor
        wts [u * 64 + 16 + rank] = ew[NKE + myi];
    }
}

// ---------------- K4: chunked speculative matching (r6 semantics, faster) ---
// spec: all chunk nodes' argmax vs chunk-start snapshot (independent -> 4-way
//       interleave per wave, banked row/gather prefetch).
// compress: keep only w>=0 entries (w==-2 prematched, w==-1 provably single).
// walk (wave 0, ascending): winners set in lane buffers; conflict -> exact
//       inline re-reduce vs fresh mbits (same-wave DS in-order).
// apply: parallel global mate/cluster writes from LDS pair buffer.
#define DPPMAX(x, ctrl) fmaxf((x), __int_as_float(__builtin_amdgcn_update_dpp( \
        (int)0xFF800000, __float_as_int(x), (ctrl), 0xf, 0xf, false)))

__device__ __forceinline__ float dpp_wavemax(float wv) {
    float m = wv;
    m = DPPMAX(m, 0x111);   // row_shr:1
    m = DPPMAX(m, 0x112);   // row_shr:2
    m = DPPMAX(m, 0x114);   // row_shr:4
    m = DPPMAX(m, 0x118);   // row_shr:8
    m = DPPMAX(m, 0x142);   // row_bcast:15
    m = DPPMAX(m, 0x143);   // row_bcast:31  -> lane 63 holds wave max
    return __int_as_float(__builtin_amdgcn_readlane(__float_as_int(m), 63));
}

// argmax over snapshot-unmatched later neighbors; -1 = no candidate
__device__ __forceinline__ int spec_reduce(int u, int nl, float wt, unsigned gw) {
    bool cand = (nl > u) && !((gw >> (nl & 31)) & 1u);
    float wv = cand ? wt : -INFINITY;
    float wmax = dpp_wavemax(wv);
    unsigned long long em = __ballot(cand && (wv == wmax));
    return em ? __builtin_amdgcn_readlane(nl, (int)__builtin_ctzll(em)) : -1;
}

// winners-set membership / append (values are BLOCK-local node ids >= 0)
#define MEMB(x) (((__ballot(b0==(x)) | __ballot(b1==(x))) | \
                  (__ballot(b2==(x)) | __ballot(b3==(x)))) != 0ULL)
#define APPW(x) { int _x=(x); \
                  if (wcnt<64)       { if (lane==wcnt)     b0=_x; } \
                  else if (wcnt<128) { if (lane==wcnt-64)  b1=_x; } \
                  else if (wcnt<192) { if (lane==wcnt-128) b2=_x; } \
                  else               { if (lane==wcnt-192) b3=_x; } wcnt++; }

__global__ __launch_bounds__(512) void k4_graclus(const int* __restrict__ nbrs,
                                                  const float* __restrict__ wts,
                                                  int* __restrict__ cluster,
                                                  int* __restrict__ mate) {
    __shared__ unsigned mbits[PER / 32 + 1];
    __shared__ int win_lds[CP];
    __shared__ int cpk_lds[CP];
    __shared__ int pair_lds[CP];
    __shared__ int pcnt_lds;
    const int base = blockIdx.x * PER;
    const int tid  = threadIdx.x;
    const int lane = tid & 63;
    const int wvid = tid >> 6;
    for (int i = tid; i < PER / 32 + 1; i += 512) mbits[i] = 0u;
    __syncthreads();
    const int*   nrow = nbrs + (size_t)base * 64;
    const float* wrow = wts  + (size_t)base * 64;

    for (int t = 0; t < PER; t += CP) {
        const int wl = (PER - t < CP) ? (PER - t) : CP;
        const int j0 = t + wvid * 32;
        // ---------- spec: 8 waves x 32 nodes, 4-way interleaved ----------
        if (j0 < PER) {
            int RN[12]; float RW[12];            // 3 banks x 4 rows
            #pragma unroll
            for (int p = 0; p < 12; ++p) {
                int rr = j0 + p; rr = rr < PER ? rr : PER - 1;
                RN[p] = nrow[(size_t)rr * 64 + lane] - base;
                RW[p] = wrow[(size_t)rr * 64 + lane];
            }
            // one mbits word covers j0..j0+31 (j0 is 32-aligned)
            unsigned hws = (unsigned)__builtin_amdgcn_readfirstlane((int)mbits[j0 >> 5]);
            unsigned gq[2][4];
            #pragma unroll
            for (int i = 0; i < 4; ++i) {
                int nl = RN[i];
                gq[0][i] = mbits[(nl < 0 ? 0 : nl) >> 5];
            }
            #pragma unroll
            for (int g = 0; g < 8; ++g) {
                if (g < 7) {                      // prefetch gathers for g+1
                    #pragma unroll
                    for (int i = 0; i < 4; ++i) {
                        int nl = RN[((g + 1) % 3) * 4 + i];
                        gq[(g + 1) & 1][i] = mbits[(nl < 0 ? 0 : nl) >> 5];
                    }
                }
                #pragma unroll
                for (int i = 0; i < 4; ++i) {     // 4 independent reduces
                    int u = j0 + g * 4 + i;
                    if (u < PER) {
                        int w;
                        if ((hws >> (g * 4 + i)) & 1u) w = -2;
                        else w = spec_reduce(u, RN[(g % 3) * 4 + i],
                                             RW[(g % 3) * 4 + i], gq[g & 1][i]);
                        if (lane == 0) win_lds[u - t] = w;
                    }
                }
                if (g < 5) {                      // load rows for g+3 into freed bank
                    #pragma unroll
                    for (int i = 0; i < 4; ++i) {
                        int rr = j0 + (g + 3) * 4 + i; rr = rr < PER ? rr : PER - 1;
                        RN[(g % 3) * 4 + i] = nrow[(size_t)rr * 64 + lane] - base;
                        RW[(g % 3) * 4 + i] = wrow[(size_t)rr * 64 + lane];
                    }
                }
            }
        }
        __syncthreads();
        // ---------- compress + walk (wave 0) ----------
        if (wvid == 0) {
            int cnt = 0;
            #pragma unroll
            for (int q = 0; q < 4; ++q) {         // stable compact of w>=0 entries
                int idx = q * 64 + lane;
                int w = (idx < wl) ? win_lds[idx] : -2;
                bool keep = (w >= 0);
                unsigned long long mk = __ballot(keep);
                int pos = cnt + (int)__popcll(mk & ((1ULL << lane) - 1ULL));
                if (keep) cpk_lds[pos] = (w << 8) | idx;   // w block-local, idx chunk-local
                cnt += (int)__popcll(mk);
            }
            int c0 = cpk_lds[lane];
            int c1 = cpk_lds[64 + lane];
            int c2 = cpk_lds[128 + lane];
            int c3 = cpk_lds[192 + lane];
            int b0 = -3, b1 = -3, b2 = -3, b3 = -3;
            int wcnt = 0, pcnt = 0;
            for (int m = 0; m < cnt; ++m) {
                int pk = (m < 64)  ? __builtin_amdgcn_readlane(c0, m)
                       : (m < 128) ? __builtin_amdgcn_readlane(c1, m - 64)
                       : (m < 192) ? __builtin_amdgcn_readlane(c2, m - 128)
                                   : __builtin_amdgcn_readlane(c3, m - 192);
                int jj = pk & 255;
                int ww = pk >> 8;
                int ug = t + jj;
                if (MEMB(ug)) continue;           // grabbed earlier this pass
                if (MEMB(ww)) {
                    // conflict (rare): exact re-reduce vs fresh state
                    int nl = nrow[(size_t)ug * 64 + lane] - base;
                    float wt2 = wrow[(size_t)ug * 64 + lane];
                    unsigned gw = mbits[(nl < 0 ? 0 : nl) >> 5];
                    int w2 = spec_reduce(ug, nl, wt2, gw);
                    if (w2 < 0) continue;         // stays single
                    ww = w2;
                }
                APPW(ww);
                if (lane == 0) {
                    atomicOr(&mbits[ug >> 5], 1u << (ug & 31));
                    atomicOr(&mbits[ww >> 5], 1u << (ww & 31));
                    pair_lds[pcnt] = (ww << 8) | jj;
                }
                pcnt++;
            }
            if (lane == 0) pcnt_lds = pcnt;
        }
        __syncthreads();
        // ---------- apply (all waves, parallel global writes) ----------
        {
            int np = pcnt_lds;
            for (int i = tid; i < np; i += 512) {
                int pk = pair_lds[i];
                int uu = base + t + (pk & 255);
                int wg = base + (pk >> 8);
                mate[uu] = wg;
                mate[wg] = uu;
                cluster[wg] = uu;
            }
        }
        __syncthreads();
    }
}

// K5: single-block inclusive scan of is_rep -> new_id, nc
__global__ __launch_bounds__(1024) void k5_scan(const int* __restrict__ cluster,
                                                int* __restrict__ newid,
                                                int* __restrict__ ncp) {
    __shared__ int wsum[16];
    __shared__ int carry;
    const int tid = threadIdx.x;
    const int lane = tid & 63;
    const int wid = tid >> 6;
    if (tid == 0) carry = 0;
    __syncthreads();
    for (int bse = 0; bse < NN; bse += 1024) {
        int u = bse + tid;
        int v = (u < NN && cluster[u] == u) ? 1 : 0;
        int s = v;
        #pragma unroll
        for (int off = 1; off < 64; off <<= 1) {
            int t = __shfl_up(s, off, 64);
            if (lane >= off) s += t;
        }
        if (lane == 63) wsum[wid] = s;
        __syncthreads();
        if (wid == 0) {
            int w2 = (lane < 16) ? wsum[lane] : 0;
            #pragma unroll
            for (int off = 1; off < 16; off <<= 1) {
                int t = __shfl_up(w2, off, 64);
                if (lane >= off) w2 += t;
            }
            if (lane < 16) wsum[lane] = w2;
        }
        __syncthreads();
        int wpre = (wid > 0) ? wsum[wid - 1] : 0;
        int carryv = carry;
        if (u < NN) newid[u] = carryv + wpre + s - 1;
        int total = wsum[15];
        __syncthreads();
        if (tid == 0) carry = carryv + total;
        __syncthreads();
    }
    if (tid == 0) *ncp = carry;
}

// K6: cluster id map + representative lookup
__global__ void k6_relabel(const int* __restrict__ cluster, const int* __restrict__ newid,
                           int* __restrict__ cmap, int* __restrict__ repof) {
    int u = blockIdx.x * blockDim.x + threadIdx.x;
    if (u >= NN) return;
    int cl = cluster[u];
    int cid = newid[cl];
    cmap[u] = cid;
    if (cl == u) repof[cid] = u;
}

// K7: max-pool features into d_out's [N,H] region + pooled batch vector
__global__ __launch_bounds__(128) void k7_pool(const float* __restrict__ h,
                                               const int* __restrict__ repof,
                                               const int* __restrict__ mate,
                                               const int* __restrict__ batch,
                                               const int* __restrict__ ncp,
                                               float* __restrict__ xout,
                                               float* __restrict__ bpool) {
    int cid = blockIdx.x;
    int tid = threadIdx.x;
    int nc = *ncp;
    if (cid >= nc) {
        #pragma unroll
        for (int q = 0; q < 3; ++q) xout[(size_t)cid * HH + tid + q * 128] = 0.f;
        if (tid == 0) bpool[cid] = 0.f;
        return;
    }
    int u = repof[cid];
    int v = mate[u];
    const float* hu = h + (size_t)u * HH;
    const float* hv = h + (size_t)(v >= 0 ? v : u) * HH;
    #pragma unroll
    for (int q = 0; q < 3; ++q) {
        int j = tid + q * 128;
        float a = hu[j];
        if (v >= 0) a = fmaxf(a, hv[j]);
        xout[(size_t)cid * HH + j] = a;
    }
    if (tid == 0) bpool[cid] = (float)batch[u];
}

// K8: per-destination-cluster candidate source lists (with duplicates)
__global__ void k8_adj(const int* __restrict__ ei, const int* __restrict__ cmap,
                       int* __restrict__ adjcnt, int* __restrict__ adj) {
    int g = blockIdx.x * blockDim.x + threadIdx.x;
    if (g >= EE) return;
    int cs = cmap[ei[g]];
    int cd = cmap[ei[EE + g]];
    if (cs == cd) return;
    int slot = atomicAdd(&adjcnt[cd], 1);
    if (slot < 128) adj[(size_t)cd * 128 + slot] = cs;
}

// K9: dedupe + sum pooled rows -> aggr
__global__ __launch_bounds__(128) void k9_aggr(const int* __restrict__ adjcnt,
                                               const int* __restrict__ adj,
                                               const float* __restrict__ x,
                                               const int* __restrict__ ncp,
                                               float* __restrict__ aggr) {
    int cid = blockIdx.x;
    int tid = threadIdx.x;
    if (cid >= *ncp) return;
    int cnt = adjcnt[cid]; if (cnt > 128) cnt = 128;
    __shared__ int vals[128];
    __shared__ int keep[128];
    if (tid < cnt) vals[tid] = adj[(size_t)cid * 128 + tid];
    __syncthreads();
    if (tid < cnt) {
        int v = vals[tid]; int k = 1;
        for (int m = 0; m < tid; ++m) if (vals[m] == v) { k = 0; break; }
        keep[tid] = k;
    }
    __syncthreads();
    float a0 = 0.f, a1 = 0.f, a2 = 0.f;
    for (int e = 0; e < cnt; ++e) {
        if (keep[e]) {
            const float* xr = x + (size_t)vals[e] * HH;
            a0 += xr[tid]; a1 += xr[tid + 128]; a2 += xr[tid + 256];
        }
    }
    aggr[(size_t)cid * HH + tid]       = a0;
    aggr[(size_t)cid * HH + tid + 128] = a1;
    aggr[(size_t)cid * HH + tid + 256] = a2;
}

// K10: out = relu([aggr | max(h_u,h_v)] @ [Wrel|Wroot]^T + b_rel)
// 128x128 tile, 8x8 accum per thread
__global__ __launch_bounds__(256) void k10_gemm(const float* __restrict__ aggr,
                                                const float* __restrict__ h,
                                                const int* __restrict__ repof,
                                                const int* __restrict__ mate,
                                                const float* __restrict__ Wrel,
                                                const float* __restrict__ Wroot,
                                                const float* __restrict__ brel,
                                                float* __restrict__ out,
                                                const int* __restrict__ ncp) {
    const int nc = *ncp;
    const int row0 = blockIdx.x * 128;
    const int col0 = blockIdx.y * 128;
    if (row0 >= nc) return;
    __shared__ float As[16][132];
    __shared__ float Ws[16][132];
    __shared__ int us[128], vs[128];
    const int tid = threadIdx.x;
    if (tid < 128) {
        int r = row0 + tid;
        int u = 0, v = -1;
        if (r < nc) { u = repof[r]; v = mate[u]; }
        us[tid] = u; vs[tid] = v;
    }
    __syncthreads();
    float acc[8][8] = {};
    const int ty = tid >> 4, tx = tid & 15;
    for (int kt = 0; kt < 2 * HH; kt += 16) {
        #pragma unroll
        for (int q = 0; q < 2; ++q) {
            int flat = tid + q * 256;           // 0..511
            int r    = flat >> 2;               // 0..127
            int kq   = (flat & 3) << 2;         // 0,4,8,12
            int k    = kt + kq;
            int grow = row0 + r;
            bool rv  = (grow < nc);
            float4 val;
            if (k < HH) {
                val = *(const float4*)(aggr + (size_t)(rv ? grow : 0) * HH + k);
            } else {
                int kk = k - HH;
                int u = us[r], v = vs[r];
                float4 a = *(const float4*)(h + (size_t)u * HH + kk);
                if (v >= 0) {
                    float4 b = *(const float4*)(h + (size_t)v * HH + kk);
                    a.x = fmaxf(a.x, b.x); a.y = fmaxf(a.y, b.y);
                    a.z = fmaxf(a.z, b.z); a.w = fmaxf(a.w, b.w);
                }
                val = a;
            }
            if (!rv) val = make_float4(0.f, 0.f, 0.f, 0.f);
            As[kq + 0][r] = val.x; As[kq + 1][r] = val.y;
            As[kq + 2][r] = val.z; As[kq + 3][r] = val.w;
        }
        {
            const float* Wsrc = (kt < HH) ? Wrel : Wroot;
            int kk0 = (kt < HH) ? kt : kt - HH;
            #pragma unroll
            for (int q = 0; q < 2; ++q) {
                int flat = tid + q * 256;
                int j    = flat >> 2;
                int kq   = (flat & 3) << 2;
                float4 w = *(const float4*)(Wsrc + (size_t)(col0 + j) * HH + kk0 + kq);
                Ws[kq + 0][j] = w.x; Ws[kq + 1][j] = w.y;
                Ws[kq + 2][j] = w.z; Ws[kq + 3][j] = w.w;
            }
        }
        __syncthreads();
        #pragma unroll
        for (int k = 0; k < 16; ++k) {
            float a[8], w[8];
            #pragma unroll
            for (int i = 0; i < 8; ++i) a[i] = As[k][ty * 8 + i];
            #pragma unroll
            for (int n = 0; n < 8; ++n) w[n] = Ws[k][tx * 8 + n];
            #pragma unroll
            for (int i = 0; i < 8; ++i)
                #pragma unroll
                for (int n = 0; n < 8; ++n)
                    acc[i][n] += a[i] * w[n];
        }
        __syncthreads();
    }
    #pragma unroll
    for (int i = 0; i < 8; ++i) {
        int r = row0 + ty * 8 + i;
        if (r >= nc) continue;
        #pragma unroll
        for (int n = 0; n < 8; ++n) {
            int j = col0 + tx * 8 + n;
            float v = acc[i][n] + brel[j];
            out[(size_t)r * HH + j] = v > 0.f ? v : 0.f;
        }
    }
}

extern "C" void kernel_launch(void* const* d_in, const int* in_sizes, int n_in,
                              void* d_out, int out_size, void* d_ws, size_t ws_size,
                              hipStream_t stream) {
    const float* h     = (const float*)d_in[0];
    const int*   ei    = (const int*)d_in[1];
    const float* ew    = (const float*)d_in[2];
    const int*   batch = (const int*)d_in[3];
    const float* Wrel  = (const float*)d_in[4];
    const float* brel  = (const float*)d_in[5];
    const float* Wroot = (const float*)d_in[6];
    float* out = (float*)d_out;

    unsigned char* w8 = (unsigned char*)d_ws;
    int*   nbrs   = (int*)(w8 + OFF_NBRS);
    float* wts    = (float*)(w8 + OFF_WTS);
    int*   adj    = (int*)(w8 + OFF_ADJ);
    int*   cnt2   = (int*)(w8 + OFF_CNT2);
    int*   adjcnt = (int*)(w8 + OFF_ADJC);
    int*   clus   = (int*)(w8 + OFF_CLUS);
    int*   mate   = (int*)(w8 + OFF_MATE);
    int*   newid  = (int*)(w8 + OFF_NEWID);
    int*   cmap   = (int*)(w8 + OFF_CMAP);
    int*   repof  = (int*)(w8 + OFF_REPOF);
    int*   ncp    = (int*)(w8 + OFF_NC);
    float* aggr   = (float*)(w8 + OFF_AGGR);

    float* xout  = out;
    float* bpool = out + (size_t)NN * HH;

    hipLaunchKernelGGL(k0_init,    dim3((NN + 255) / 256), dim3(256), 0, stream, cnt2, adjcnt, clus, mate);
    hipLaunchKernelGGL(k1_build,   dim3((NN * 64 + 255) / 256), dim3(256), 0, stream, ei, ew, nbrs, wts);
    hipLaunchKernelGGL(k2_scatter, dim3((NKE + 255) / 256), dim3(256), 0, stream, ei, cnt2, nbrs);
    hipLaunchKernelGGL(k3_rank,    dim3((NN * 64 + 255) / 256), dim3(256), 0, stream, cnt2, ew, nbrs, wts);
    hipLaunchKernelGGL(k4_graclus, dim3(8), dim3(512), 0, stream, nbrs, wts, clus, mate);
    hipLaunchKernelGGL(k5_scan,    dim3(1), dim3(1024), 0, stream, clus, newid, ncp);
    hipLaunchKernelGGL(k6_relabel, dim3((NN + 255) / 256), dim3(256), 0, stream, clus, newid, cmap, repof);
    hipLaunchKernelGGL(k7_pool,    dim3(NN), dim3(128), 0, stream, h, repof, mate, batch, ncp, xout, bpool);
    hipLaunchKernelGGL(k8_adj,     dim3((EE + 255) / 256), dim3(256), 0, stream, ei, cmap, adjcnt, adj);
    hipLaunchKernelGGL(k9_aggr,    dim3(NN), dim3(128), 0, stream, adjcnt, adj, xout, ncp, aggr);
    hipLaunchKernelGGL(k10_gemm,   dim3((NN + 127) / 128, HH / 128), dim3(256), 0, stream,
                       aggr, h, repof, mate, Wrel, Wroot, brel, out, ncp);
}